// Round 1
// baseline (1513.580 us; speedup 1.0000x reference)
//
#include <hip/hip_runtime.h>
#include <hip/hip_bf16.h>
#include <stdint.h>

#define LL 512
#define BB 64
#define CC 512

typedef float float4v __attribute__((ext_vector_type(4)));

// ws layout:
//   [0, 262144)        : E8  = fp8(exp(trans))^T, layout [j][k], row stride 512 bytes
//   [262144, 262148)   : float scoreAcc
//   [262148, 262404)   : float logzArr[64]
#define WS_SCORE 262144
#define WS_LOGZ  262148

__device__ __forceinline__ bool mask_at(const void* maskp, bool is_byte, int t, int b) {
    if (is_byte) return ((const unsigned char*)maskp)[t * BB + b] != 0;
    return ((const int*)maskp)[t * BB + b] != 0;
}

// ---------------- prep: build E8 = fp8(exp(trans))^T, zero score accumulator ----------
__global__ void prep_kernel(const float* __restrict__ trans, unsigned char* __restrict__ ws) {
    int g = blockIdx.x * blockDim.x + threadIdx.x;
    if (g == 0) *(float*)(ws + WS_SCORE) = 0.0f;
    if (g >= 512 * 128) return;
    int j  = g & 511;      // output row (N index)
    int k4 = g >> 9;       // dword along k
    float e0 = __expf(trans[(4 * k4 + 0) * CC + j]);
    float e1 = __expf(trans[(4 * k4 + 1) * CC + j]);
    float e2 = __expf(trans[(4 * k4 + 2) * CC + j]);
    float e3 = __expf(trans[(4 * k4 + 3) * CC + j]);
    int r = 0;
    r = __builtin_amdgcn_cvt_pk_fp8_f32(e0, e1, r, false);
    r = __builtin_amdgcn_cvt_pk_fp8_f32(e2, e3, r, true);
    ((int*)ws)[j * 128 + k4] = r;
}

// ---------------- main scan: 4 wgs x 512 thr, 16 chains per wg -----------------------
// Per-step (prob space): p = v / max(v) (fp8); w = p @ E (MFMA); v' = w * exp(emit_t);
// S += log(max(v)).  E-fragments live in VGPRs for the whole kernel.
__launch_bounds__(512, 2)
__global__ void crf_scan_kernel(const float* __restrict__ emit,
                                const void* __restrict__ maskp,
                                const float* __restrict__ tfs,
                                const float* __restrict__ t2e,
                                unsigned char* __restrict__ ws) {
    __shared__ __align__(16) float vbuf[16 * 516];          // v state, row stride 516 floats
    __shared__ __align__(16) unsigned char p8[16 * 528];    // fp8 p, row stride 528 bytes
    __shared__ unsigned char maskL[512 * 16];
    __shared__ float mbuf[2][16];                            // row max, parity buffered
    __shared__ float Sv[16];                                 // log-scale accumulator
    __shared__ float red[16][32];

    const int tid = threadIdx.x;
    const int B0  = blockIdx.x * 16;
    const bool is_byte = ((const unsigned char*)maskp)[1] != 0;

    // preload mask for this wg's 16 chains
    for (int idx = tid; idx < 512 * 16; idx += 512) {
        int t = idx >> 4, c = idx & 15;
        maskL[idx] = mask_at(maskp, is_byte, t, B0 + c) ? 1 : 0;
    }

    const int wv   = tid >> 6;   // wave 0..7, owns n-tiles wv*4..wv*4+3
    const int lane = tid & 63;
    const int q    = lane >> 4;  // k-group / row-group
    const int r15  = lane & 15;  // B col / A row within tile

    // E fragments: resident in VGPRs for all 511 steps (128 VGPRs of fp8)
    long long ef[4][16];
#pragma unroll
    for (int nt = 0; nt < 4; ++nt) {
        int j = (wv * 4 + nt) * 16 + r15;
#pragma unroll
        for (int kk = 0; kk < 16; ++kk)
            ef[nt][kk] = *(const long long*)(ws + j * 512 + kk * 32 + q * 8);
    }

    const int c5 = tid >> 5;  // chain 0..15
    const int s5 = tid & 31;  // slice 0..31

    // ---- init t = 0: alpha0 = emit[0] + tfs; v = exp(alpha0 - max); S = max ----
    {
        float lmax = -3.0e38f;
#pragma unroll
        for (int i = 0; i < 4; ++i) {
            int j4 = s5 + 32 * i;
            float4v em = *(const float4v*)(emit + (size_t)(B0 + c5) * CC + 4 * j4);
            float4v tf = *(const float4v*)(tfs + 4 * j4);
            float4v a = em + tf;
            *(float4v*)(vbuf + c5 * 516 + 4 * j4) = a;
            lmax = fmaxf(lmax, fmaxf(fmaxf(a.x, a.y), fmaxf(a.z, a.w)));
        }
        red[c5][s5] = lmax;
    }
    __syncthreads();
    if (tid < 16) {
        float m0 = red[tid][0];
        for (int s = 1; s < 32; ++s) m0 = fmaxf(m0, red[tid][s]);
        Sv[tid] = m0;
        mbuf[1][tid] = 1.0f;   // max of exp(alpha - m0) is exactly 1
    }
    __syncthreads();
    {
        float m0 = Sv[c5];
#pragma unroll
        for (int i = 0; i < 4; ++i) {
            int j4 = s5 + 32 * i;
            float4v a = *(const float4v*)(vbuf + c5 * 516 + 4 * j4);
            a.x = __expf(a.x - m0); a.y = __expf(a.y - m0);
            a.z = __expf(a.z - m0); a.w = __expf(a.w - m0);
            *(float4v*)(vbuf + c5 * 516 + 4 * j4) = a;
        }
    }
    __syncthreads();

    // ---- main loop ----
    for (int t = 1; t < LL; ++t) {
        const int pp = t & 1;
        // phase A: build p8 = fp8(v / m); bookkeeping for m and S
        {
            float m  = mbuf[pp][c5];
            float rc = 1.0f / m;
            bool act = maskL[t * 16 + c5] != 0;
            if (s5 == 0) {
                mbuf[pp ^ 1][c5] = act ? 0.0f : m;  // epilogue atomicMax only if active
                if (act) Sv[c5] += __logf(m);
            }
#pragma unroll
            for (int i = 0; i < 4; ++i) {
                int j4 = s5 + 32 * i;
                float4v v = *(const float4v*)(vbuf + c5 * 516 + 4 * j4);
                int r = 0;
                r = __builtin_amdgcn_cvt_pk_fp8_f32(v.x * rc, v.y * rc, r, false);
                r = __builtin_amdgcn_cvt_pk_fp8_f32(v.z * rc, v.w * rc, r, true);
                *(int*)(p8 + c5 * 528 + 4 * j4) = r;
            }
        }
        __syncthreads();
        // phase B: emit prefetch, MFMA, epilogue (v' = w * exp(emit), new row max)
        {
            float em[4][4];
#pragma unroll
            for (int nt = 0; nt < 4; ++nt)
#pragma unroll
                for (int rr = 0; rr < 4; ++rr)
                    em[nt][rr] = emit[(size_t)(t * BB + B0 + q * 4 + rr) * CC + (wv * 4 + nt) * 16 + r15];

            float4v acc[4];
            const float4v z = {0.f, 0.f, 0.f, 0.f};
#pragma unroll
            for (int nt = 0; nt < 4; ++nt) acc[nt] = z;
#pragma unroll
            for (int kk = 0; kk < 16; ++kk) {
                long long a = *(const long long*)(p8 + r15 * 528 + kk * 32 + q * 8);
#pragma unroll
                for (int nt = 0; nt < 4; ++nt)
                    acc[nt] = __builtin_amdgcn_mfma_f32_16x16x32_fp8_fp8(a, ef[nt][kk], acc[nt], 0, 0, 0);
            }
            float rowmax[4] = {0.f, 0.f, 0.f, 0.f};
#pragma unroll
            for (int nt = 0; nt < 4; ++nt) {
                int j = (wv * 4 + nt) * 16 + r15;
#pragma unroll
                for (int rr = 0; rr < 4; ++rr) {
                    int c = q * 4 + rr;                 // C/D: row = (lane>>4)*4 + reg
                    float wv_ = acc[nt][rr];
                    float vn  = wv_ * __expf(em[nt][rr]);
                    if (maskL[t * 16 + c]) vbuf[c * 516 + j] = vn;
                    rowmax[rr] = fmaxf(rowmax[rr], vn);
                }
            }
#pragma unroll
            for (int rr = 0; rr < 4; ++rr) {
                float mr = rowmax[rr];
                mr = fmaxf(mr, __shfl_xor(mr, 1));
                mr = fmaxf(mr, __shfl_xor(mr, 2));
                mr = fmaxf(mr, __shfl_xor(mr, 4));
                mr = fmaxf(mr, __shfl_xor(mr, 8));
                if (r15 == 0) {
                    int c = q * 4 + rr;
                    if (maskL[t * 16 + c])
                        atomicMax((int*)&mbuf[pp ^ 1][c], __float_as_int(mr));  // vn > 0 always
                }
            }
        }
        __syncthreads();
    }

    // ---- final: logz_b = S + log( sum_j v_j * exp(t2e_j) ) ----
    {
        float part = 0.0f;
#pragma unroll
        for (int i = 0; i < 4; ++i) {
            int j4 = s5 + 32 * i;
            float4v v  = *(const float4v*)(vbuf + c5 * 516 + 4 * j4);
            float4v te = *(const float4v*)(t2e + 4 * j4);
            part += v.x * __expf(te.x) + v.y * __expf(te.y)
                  + v.z * __expf(te.z) + v.w * __expf(te.w);
        }
        red[c5][s5] = part;
    }
    __syncthreads();
    if (tid < 16) {
        float s = 0.0f;
        for (int i = 0; i < 32; ++i) s += red[tid][i];
        ((float*)(ws + WS_LOGZ))[B0 + tid] = Sv[tid] + __logf(s);
    }
}

// ---------------- score: gather terms, atomic accumulate -----------------------------
__global__ void score_kernel(const float* __restrict__ emit,
                             const int* __restrict__ target,
                             const void* __restrict__ maskp,
                             const float* __restrict__ trans,
                             const float* __restrict__ tfs,
                             const float* __restrict__ t2e,
                             unsigned char* __restrict__ ws) {
    const bool is_byte = ((const unsigned char*)maskp)[1] != 0;
    int g = blockIdx.x * blockDim.x + threadIdx.x;
    float val = 0.0f;
    for (int e = g; e < LL * BB; e += gridDim.x * blockDim.x) {
        int t = e >> 6, b = e & 63;
        if (mask_at(maskp, is_byte, t, b)) {
            int tg  = target[t * BB + b];
            float v = emit[(size_t)(t * BB + b) * CC + tg];
            if (t > 0) v += trans[(size_t)target[(t - 1) * BB + b] * CC + tg];
            val += v;
        }
    }
    if (blockIdx.x == 0 && threadIdx.x < BB) {
        int b = threadIdx.x;
        val += tfs[target[b]];
        // lens = first t with mask false (mask is prefix-true); binary search
        int lo = 0, hi = LL;
        while (lo < hi) {
            int mid = (lo + hi) >> 1;
            if (mask_at(maskp, is_byte, mid, b)) lo = mid + 1; else hi = mid;
        }
        val += t2e[target[(lo - 1) * BB + b]];
    }
    for (int off = 32; off > 0; off >>= 1) val += __shfl_down(val, off);
    if ((threadIdx.x & 63) == 0) atomicAdd((float*)(ws + WS_SCORE), val);
}

// ---------------- combine: out = (sum logz - score)/B --------------------------------
__global__ void combine_kernel(const unsigned char* __restrict__ ws, float* __restrict__ out) {
    float v = ((const float*)(ws + WS_LOGZ))[threadIdx.x];
    for (int off = 32; off > 0; off >>= 1) v += __shfl_down(v, off);
    if (threadIdx.x == 0) out[0] = (v - *(const float*)(ws + WS_SCORE)) * (1.0f / 64.0f);
}

extern "C" void kernel_launch(void* const* d_in, const int* in_sizes, int n_in,
                              void* d_out, int out_size, void* d_ws, size_t ws_size,
                              hipStream_t stream) {
    const float* emit   = (const float*)d_in[0];
    const int*   target = (const int*)d_in[1];
    const void*  maskp  = d_in[2];
    const float* trans  = (const float*)d_in[3];
    const float* tfs    = (const float*)d_in[4];
    const float* t2e    = (const float*)d_in[5];
    unsigned char* ws   = (unsigned char*)d_ws;
    float* out          = (float*)d_out;

    prep_kernel<<<256, 256, 0, stream>>>(trans, ws);
    crf_scan_kernel<<<4, 512, 0, stream>>>(emit, maskp, tfs, t2e, ws);
    score_kernel<<<32, 256, 0, stream>>>(emit, target, maskp, trans, tfs, t2e, ws);
    combine_kernel<<<1, 64, 0, stream>>>(ws, out);
}